// Round 2
// baseline (775.731 us; speedup 1.0000x reference)
//
#include <hip/hip_runtime.h>

// LISTA fused kernel, MI355X gfx950.  Round 2.
// X[4][64][65536] f32, We[256][64] f32, S[3][256][256] f32, thetas[4], out[4][256][65536] f32.
// 1 WG (4 waves) per 64-pixel tile; wave w owns dict slice [64w,64w+64).
// MFMA 16x16x32 bf16, A=weights, B=activations => C/D col=pixel,row=dict:
// lane holds 4 consecutive dict entries -> packed b64 LDS epilogue writes.
// R2: med3 shrink + HW pk-bf16 cvt (VALU diet), S-frags streamed in 4 bursts
// (32 VGPR instead of 128 -> 3 WGs/CU), packed b128 lX staging.

#define TM 64
#define LA_STRIDE 264   // 256 + 8 bf16 pad (528B rows: 16B aligned, near-minimal banks)
#define LX_STRIDE 72    // 64 + 8

typedef short bf16x8 __attribute__((ext_vector_type(8)));
typedef float f32x4 __attribute__((ext_vector_type(4)));

__device__ __forceinline__ unsigned short f2bf(float f) {
  union { float f; unsigned u; } a; a.f = f;
  return (unsigned short)((a.u + 0x7fffu + ((a.u >> 16) & 1u)) >> 16); // RNE
}

__device__ __forceinline__ unsigned pk_bf16(float a, float b) {
#if __has_builtin(__builtin_amdgcn_cvt_pk_bf16_f32)
  typedef __bf16 bf16x2_t __attribute__((ext_vector_type(2)));
  bf16x2_t r = __builtin_amdgcn_cvt_pk_bf16_f32(a, b);
  return __builtin_bit_cast(unsigned, r);
#else
  return (unsigned)f2bf(a) | ((unsigned)f2bf(b) << 16);
#endif
}

__device__ __forceinline__ float bf2f_lo(unsigned u) {
  union { unsigned u; float f; } a; a.u = u << 16; return a.f;
}
__device__ __forceinline__ float bf2f_hi(unsigned u) {
  union { unsigned u; float f; } a; a.u = u & 0xffff0000u; return a.f;
}
__device__ __forceinline__ float sshrink(float x, float th) {
  return x - __builtin_amdgcn_fmed3f(x, -th, th);
}

template<bool WBF16>
__device__ __forceinline__ bf16x8 load_wfrag(const unsigned short* wbase,
                                             const float* fbase, int off) {
  if constexpr (WBF16) {
    return *reinterpret_cast<const bf16x8*>(wbase + off);
  } else {
    const float* p = fbase + off;
    float4 f0 = *reinterpret_cast<const float4*>(p);
    float4 f1 = *reinterpret_cast<const float4*>(p + 4);
    bf16x8 t;
    t[0] = (short)f2bf(f0.x); t[1] = (short)f2bf(f0.y);
    t[2] = (short)f2bf(f0.z); t[3] = (short)f2bf(f0.w);
    t[4] = (short)f2bf(f1.x); t[5] = (short)f2bf(f1.y);
    t[6] = (short)f2bf(f1.z); t[7] = (short)f2bf(f1.w);
    return t;
  }
}

__global__ void convert_weights(const float* __restrict__ We,
                                const float* __restrict__ S,
                                unsigned short* __restrict__ w) {
  int gid = blockIdx.x * 256 + threadIdx.x;
  if (gid < 256 * 64) w[gid] = f2bf(We[gid]);
  else if (gid < 256 * 64 + 3 * 256 * 256) w[gid] = f2bf(S[gid - 256 * 64]);
}

template<bool WBF16>
__global__ __launch_bounds__(256, 3)
void lista_kernel(const float* __restrict__ X, const float* __restrict__ Wef,
                  const float* __restrict__ Sf, const float* __restrict__ thetas,
                  float* __restrict__ out,
                  const unsigned short* __restrict__ wWe,
                  const unsigned short* __restrict__ wS) {
  __shared__ unsigned short lA[TM * LA_STRIDE]; // logits tile [pixel][dict] bf16
  __shared__ unsigned short lX[TM * LX_STRIDE]; // input tile  [pixel][chan] bf16

  const int tid  = threadIdx.x;
  const int wave = tid >> 6;
  const int lane = tid & 63;
  const int l16  = lane & 15;
  const int quad = lane >> 4;
  const int p0   = blockIdx.x * TM;
  const int b0   = p0 >> 16;
  const int s0   = p0 & 65535;
  const int d_base = wave * 64;

  // ---- stage X tile -> lX. Loads coalesced (64 consecutive spatials / instr);
  // writes: thread holds 16 consecutive channels of one pixel -> 2x ds_write_b128.
  {
    const int m = tid & 63;
    const int cg = tid >> 6;
    float v[16];
#pragma unroll
    for (int j = 0; j < 16; ++j)
      v[j] = X[(b0 * 64 + cg * 16 + j) * 65536 + s0 + m];
    unsigned pk[8];
#pragma unroll
    for (int j = 0; j < 8; ++j) pk[j] = pk_bf16(v[2 * j], v[2 * j + 1]);
    uint4* dst = reinterpret_cast<uint4*>(&lX[m * LX_STRIDE + cg * 16]);
    dst[0] = make_uint4(pk[0], pk[1], pk[2], pk[3]);
    dst[1] = make_uint4(pk[4], pk[5], pk[6], pk[7]);
  }

  // ---- We fragments (A-operand)
  bf16x8 Wf1[4][2];
#pragma unroll
  for (int dt = 0; dt < 4; ++dt)
#pragma unroll
    for (int ks = 0; ks < 2; ++ks) {
      const int off = (d_base + dt * 16 + l16) * 64 + ks * 32 + quad * 8;
      Wf1[dt][ks] = load_wfrag<WBF16>(wWe, Wef, off);
    }

  __syncthreads();

  // ---- GEMM1: B0[d][p] = sum_c We[d][c]*X[p][c]
  f32x4 acc[4][4];
#pragma unroll
  for (int dt = 0; dt < 4; ++dt)
#pragma unroll
    for (int pt = 0; pt < 4; ++pt) acc[dt][pt] = (f32x4){0.f, 0.f, 0.f, 0.f};

#pragma unroll
  for (int ks = 0; ks < 2; ++ks) {
    bf16x8 bfr[4];
#pragma unroll
    for (int pt = 0; pt < 4; ++pt)
      bfr[pt] = *reinterpret_cast<const bf16x8*>(
          &lX[(pt * 16 + l16) * LX_STRIDE + ks * 32 + quad * 8]);
#pragma unroll
    for (int pt = 0; pt < 4; ++pt)
#pragma unroll
      for (int dt = 0; dt < 4; ++dt)
        acc[dt][pt] = __builtin_amdgcn_mfma_f32_16x16x32_bf16(
            Wf1[dt][ks], bfr[pt], acc[dt][pt], 0, 0, 0);
  }

  // ---- phase-0 epilogue: B0 packed bf16 -> regs; logits0 = shrink(B0) -> lA
  const float th0 = thetas[0];
  unsigned B0pk[4][4][2];
#pragma unroll
  for (int dt = 0; dt < 4; ++dt)
#pragma unroll
    for (int pt = 0; pt < 4; ++pt) {
      float v0 = acc[dt][pt][0], v1 = acc[dt][pt][1];
      float v2 = acc[dt][pt][2], v3 = acc[dt][pt][3];
      B0pk[dt][pt][0] = pk_bf16(v0, v1);
      B0pk[dt][pt][1] = pk_bf16(v2, v3);
      unsigned pk0 = pk_bf16(sshrink(v0, th0), sshrink(v1, th0));
      unsigned pk1 = pk_bf16(sshrink(v2, th0), sshrink(v3, th0));
      const int row = pt * 16 + l16;
      const int col = d_base + dt * 16 + quad * 4;
      *reinterpret_cast<uint2*>(&lA[row * LA_STRIDE + col]) = make_uint2(pk0, pk1);
    }

  // ---- LISTA iterations (dynamic loop: keeps S loads from being hoisted)
  bf16x8 Wf[4][2]; // streamed quarter-buffer: 32 VGPRs
#pragma unroll 1
  for (int it = 0; it < 3; ++it) {
    const float th = thetas[it + 1];
    const int sbase = it * 65536;

    // burst 0 issued before the barrier (latency hides in barrier wait)
#pragma unroll
    for (int dt = 0; dt < 4; ++dt)
#pragma unroll
      for (int k2 = 0; k2 < 2; ++k2)
        Wf[dt][k2] = load_wfrag<WBF16>(wS, Sf,
            sbase + (d_base + dt * 16 + l16) * 256 + k2 * 32 + quad * 8);

    // init acc = B0 (bf16-rounded); MFMA accumulates feat on top
#pragma unroll
    for (int dt = 0; dt < 4; ++dt)
#pragma unroll
      for (int pt = 0; pt < 4; ++pt) {
        acc[dt][pt][0] = bf2f_lo(B0pk[dt][pt][0]);
        acc[dt][pt][1] = bf2f_hi(B0pk[dt][pt][0]);
        acc[dt][pt][2] = bf2f_lo(B0pk[dt][pt][1]);
        acc[dt][pt][3] = bf2f_hi(B0pk[dt][pt][1]);
      }

    __syncthreads(); // prev lA writes -> this iter's reads

#pragma unroll
    for (int ksp = 0; ksp < 4; ++ksp) {
      if (ksp > 0) { // stream next burst (WAR on Wf: prev MFMAs consumed them)
#pragma unroll
        for (int dt = 0; dt < 4; ++dt)
#pragma unroll
          for (int k2 = 0; k2 < 2; ++k2)
            Wf[dt][k2] = load_wfrag<WBF16>(wS, Sf,
                sbase + (d_base + dt * 16 + l16) * 256 + (ksp * 2 + k2) * 32 + quad * 8);
      }
#pragma unroll
      for (int k2 = 0; k2 < 2; ++k2) {
        const int ks = ksp * 2 + k2;
        bf16x8 bfr[4];
#pragma unroll
        for (int pt = 0; pt < 4; ++pt)
          bfr[pt] = *reinterpret_cast<const bf16x8*>(
              &lA[(pt * 16 + l16) * LA_STRIDE + ks * 32 + quad * 8]);
#pragma unroll
        for (int pt = 0; pt < 4; ++pt)
#pragma unroll
          for (int dt = 0; dt < 4; ++dt)
            acc[dt][pt] = __builtin_amdgcn_mfma_f32_16x16x32_bf16(
                Wf[dt][k2], bfr[pt], acc[dt][pt], 0, 0, 0);
      }
    }

    __syncthreads(); // all lA reads done before epilogue overwrites

    if (it < 2) {
#pragma unroll
      for (int dt = 0; dt < 4; ++dt)
#pragma unroll
        for (int pt = 0; pt < 4; ++pt) {
          unsigned pk0 = pk_bf16(sshrink(acc[dt][pt][0], th), sshrink(acc[dt][pt][1], th));
          unsigned pk1 = pk_bf16(sshrink(acc[dt][pt][2], th), sshrink(acc[dt][pt][3], th));
          const int row = pt * 16 + l16;
          const int col = d_base + dt * 16 + quad * 4;
          *reinterpret_cast<uint2*>(&lA[row * LA_STRIDE + col]) = make_uint2(pk0, pk1);
        }
    } else {
#pragma unroll
      for (int dt = 0; dt < 4; ++dt)
#pragma unroll
        for (int pt = 0; pt < 4; ++pt) {
          const int d = d_base + dt * 16 + quad * 4;
          const size_t ob = (size_t)(b0 * 256 + d) * 65536 + s0 + pt * 16 + l16;
          out[ob]               = sshrink(acc[dt][pt][0], th);
          out[ob + 65536]       = sshrink(acc[dt][pt][1], th);
          out[ob + 2 * 65536]   = sshrink(acc[dt][pt][2], th);
          out[ob + 3 * 65536]   = sshrink(acc[dt][pt][3], th);
        }
    }
  }
}

extern "C" void kernel_launch(void* const* d_in, const int* in_sizes, int n_in,
                              void* d_out, int out_size, void* d_ws, size_t ws_size,
                              hipStream_t stream) {
  const float* X  = (const float*)d_in[0];
  const float* We = (const float*)d_in[1];
  const float* S  = (const float*)d_in[2];
  const float* th = (const float*)d_in[3];
  float* out = (float*)d_out;

  const size_t welems = 256 * 64 + 3 * 256 * 256; // 212992
  const bool wb = ws_size >= welems * 2;

  if (wb) {
    unsigned short* w = (unsigned short*)d_ws;
    convert_weights<<<dim3(832), dim3(256), 0, stream>>>(We, S, w);
    lista_kernel<true><<<dim3(4096), dim3(256), 0, stream>>>(
        X, We, S, th, out, w, w + 256 * 64);
  } else {
    lista_kernel<false><<<dim3(4096), dim3(256), 0, stream>>>(
        X, We, S, th, out, nullptr, nullptr);
  }
}